// Round 6
// baseline (435.951 us; speedup 1.0000x reference)
//
#include <hip/hip_runtime.h>

// CrossAttention (B=8, Sq=Skv=2048, D=1024), fp32 in/out, bf16 MFMA compute.
//
// Pipeline (5 dispatches; ws 107 MB; Q AND K parked in d_out as bf16):
//   1) cvt_all: {x,ctx}->bf16 ws; {Wq*(1/32),Wk,Wv}->bf16 ws   [one kernel]
//   2) [Q|K] = [x|ctx] @ [Wq|Wk]^T  (one batched NT GEMM) -> d_out bf16
//      Vt[b,e,t] = Wv@ctx^T (V transposed so PV is NT)    -> ws
//   3) S[b,s,t] = Q@K^T (8 batches) -> bf16 S overlays dead xbf+cbf
//   4) row_stats: per row m=max, r=1/sum(exp(s-m)) -> 128KB overlaying
//      dead Wqb (S itself is NOT rewritten — saves the softmax kernel's
//      128MB round trip)
//   5) PV GEMM with SM=true: stages raw S via global_load_lds, then each
//      thread exp-transforms ITS OWN staged LDS slots (per-wave vmcnt(0)
//      already ordered its own gloads; lgkmcnt(0) before the publish
//      barrier) and the epilogue multiplies by r[row]. out f32 -> d_out.
//
// GEMM core (unchanged from r5, 914 TF): 256x256 tile, BK=64, 8 waves
// (2Mx4N), 128KiB static LDS dbuf, counted-lgkm reads-ahead, one barrier
// per K-tile, asm ds_read_b128, XOR swizzle (0 bank conflicts, r2),
// XCD-aware 1D grid swizzle. Grid MUST equal nx*ny*nz, divisible by 8.
// Five source schedules (r0-r5) all measured ~35% MfmaUtil / ~910 TF =
// the documented m97-class ceiling; this round attacks the non-GEMM bill.

typedef unsigned short u16;
typedef __bf16 bf16x8 __attribute__((ext_vector_type(8)));
typedef float f32x4 __attribute__((ext_vector_type(4)));
typedef u16 us8 __attribute__((ext_vector_type(8)));

__device__ __forceinline__ u16 f2bf(float f) {
  unsigned int u = __float_as_uint(f);
  u += 0x7fffu + ((u >> 16) & 1u);   // round-to-nearest-even
  return (u16)(u >> 16);
}
__device__ __forceinline__ float bf2f(u16 h) {
  return __uint_as_float((unsigned int)h << 16);
}

struct __attribute__((aligned(8))) us4 { u16 x, y, z, w; };

// All fp32->bf16 converts in ONE dispatch (35840 blocks):
//   i in [0,4194304): x        -> dxc[i]
//   i in [4194304,8388608): ctx -> dxc[i]
//   j=i-8388608 in [0,786432): Wq*(1/32) | Wk | Wv -> dw[j]
__global__ __launch_bounds__(256) void cvt_all(
    const float4* __restrict__ x, const float4* __restrict__ c,
    const float4* __restrict__ wq, const float4* __restrict__ wk,
    const float4* __restrict__ wv,
    us4* __restrict__ dxc, us4* __restrict__ dw) {
  int i = blockIdx.x * 256 + threadIdx.x;
  const float4* s; us4* d; float sc = 1.0f;
  if (i < 4194304)      { s = x + i;            d = dxc + i; }
  else if (i < 8388608) { s = c + (i - 4194304); d = dxc + i; }
  else {
    int j = i - 8388608;
    if (j < 262144)      { s = wq + j;            sc = 0.03125f; }
    else if (j < 524288) { s = wk + (j - 262144); }
    else                 { s = wv + (j - 524288); }
    d = dw + j;
  }
  float4 v = *s;
  us4 o{f2bf(v.x * sc), f2bf(v.y * sc), f2bf(v.z * sc), f2bf(v.w * sc)};
  *d = o;
}

// C-style casts: static_cast cannot both drop const and change address space.
__device__ __forceinline__ void gload16(const u16* g, u16* l) {
  __builtin_amdgcn_global_load_lds(
      (const __attribute__((address_space(1))) unsigned int*)g,
      (__attribute__((address_space(3))) unsigned int*)l,
      16, 0, 0);
}

// NT GEMM: C[m,n] = sum_k A[m,k]*B[n,k].  A:[M][lda] B:[N][ldb] bf16
// row-major. 1D grid of EXACTLY nx*ny*nz blocks (divisible by 8), 512 thr.
// SM=true (PV): A is raw softmax logits; stats[row]={m, 1/sum}. Staged A
// is exp(s-m)-transformed in LDS before publish; epilogue scales by r.
template <bool BF16OUT, bool SM>
__global__ __launch_bounds__(512, 2) void gemm_nt(
    const u16* __restrict__ A, const u16* __restrict__ B, void* __restrict__ Cout,
    int lda, int ldb, int ldc, int K,
    long batchA, long batchB, long batchC, int nx, int ny,
    const float2* __restrict__ stats) {
  __shared__ u16 lds[65536];   // 128 KiB static
  __shared__ float rbuf[256];  // SM: per-row 1/sum for the epilogue
  // layout (u16 offs): buf b at b*32768; A k-half h at +h*8192 (256x32),
  // B at +16384 (+h*8192). Within a k-half: row r at r*32, 4 slots of 8.

  const int p    = blockIdx.x;
  const int slab = gridDim.x >> 3;
  const int gid  = (p & 7) * slab + (p >> 3);
  const int bx   = gid % nx;
  const int t2   = gid / nx;
  const int by   = t2 % ny;
  const int z    = t2 / ny;

  const int tid  = threadIdx.x;          // 0..511
  const int lane = tid & 63;
  const int wv   = tid >> 6;             // wave 0..7

  const u16* Ab = A + (size_t)z * batchA + (size_t)by * 256 * lda;
  const u16* Bb = B + (size_t)z * batchB + (size_t)bx * 256 * ldb;

  // staging: 512 threads, 4/row (64-B runs), 2 instrs cover 256 rows.
  // global col-group pre-swizzled: c = (tid&3) ^ ((row>>1)&3), row=tid>>2.
  const int srow = tid >> 2;                              // 0..127
  const int scol = ((tid & 3) ^ ((tid >> 3) & 3)) * 8;    // swizzled source

  const u16* gA = Ab + (size_t)srow * lda + scol;
  const u16* gB = Bb + (size_t)srow * ldb + scol;
  const size_t a128 = (size_t)128 * lda, b128 = (size_t)128 * ldb;

  u16* dA = &lds[tid * 8];           // + buf*32768 + h*8192 (+4096 instr 1)
  u16* dB = &lds[16384 + tid * 8];

  // SM: row stats for this thread's two staged A-rows + epilogue r-table.
  float mrow0 = 0.f, mrow1 = 0.f;
  if constexpr (SM) {
    const float2* st = stats + (size_t)z * 2048 + by * 256;
    mrow0 = st[srow].x;
    mrow1 = st[srow + 128].x;
    if (tid < 256) rbuf[tid] = st[tid].y;
  }

  // fragment addressing (per wave: 128x64 tile, 8x4 frags of 16x16x32)
  const int fr = lane & 15;              // m (A) / n (B) within 16
  // phys slot = k-slot(lane>>4) ^ ((row>>1)&3); row>>1&3 == (fr>>1)&3 for
  // all mi/ni/wm/wn (all multiples of 8 rows) -> lane-constant xor.
  const int xw = (((lane >> 4) ^ ((lane >> 1) & 3)) * 8);
  const int wm = (wv >> 2) * 128;        // wave m-offset (0 or 128)
  const int wn = (wv & 3) * 64;          // wave n-offset (0..192)
  const int rA = (wm + fr) * 32 + xw;    // u16 offset within A k-half
  const int rB = (wn + fr) * 32 + xw;

  // byte addresses for inline-asm ds_read (buffer 0; buffer 1 = +65536 B)
  const unsigned ldsb = (unsigned)(size_t)&lds[0];
  const unsigned bA0 = ldsb + (unsigned)(rA * 2);
  const unsigned bB0 = ldsb + 32768u + (unsigned)(rB * 2);

  f32x4 acc[8][4];
#pragma unroll
  for (int i = 0; i < 8; i++)
#pragma unroll
    for (int j = 0; j < 4; j++) acc[i][j] = (f32x4)0.f;

  const int NTt = K >> 6;                // BK=64 tiles

#define STAGE_A(BUF, KT, H) do {                                  \
    const u16* g_ = gA + (size_t)(KT) * 64 + (H) * 32;            \
    u16* d_ = dA + ((BUF) << 15) + (H) * 8192;                    \
    gload16(g_, d_); gload16(g_ + a128, d_ + 4096); } while (0)
#define STAGE_B(BUF, KT, H) do {                                  \
    const u16* g_ = gB + (size_t)(KT) * 64 + (H) * 32;            \
    u16* d_ = dB + ((BUF) << 15) + (H) * 8192;                    \
    gload16(g_, d_); gload16(g_ + b128, d_ + 4096); } while (0)
// SM: exp-transform this thread's 4 staged A-slots in buffer BUFO (u16 off).
// Slots: {+0:(h0,srow,m0)} {+4096:(h0,srow+128,m1)} {+8192:(h1,srow,m0)}
// {+12288:(h1,srow+128,m1)}. Own-slot only: per-wave vmcnt(0) suffices.
#define XFORM(BUFO) do { if constexpr (SM) {                      \
    u16* xb_ = dA + (BUFO);                                       \
    _Pragma("unroll")                                             \
    for (int s_ = 0; s_ < 4; s_++) {                              \
      u16* p_ = xb_ + (s_ & 1) * 4096 + (s_ >> 1) * 8192;         \
      const float mm_ = (s_ & 1) ? mrow1 : mrow0;                 \
      us8 v_ = *(us8*)p_;                                         \
      _Pragma("unroll")                                           \
      for (int k_ = 0; k_ < 8; k_++)                              \
        v_[k_] = f2bf(__expf(bf2f(v_[k_]) - mm_));                \
      *(us8*)p_ = v_;                                             \
    }                                                             \
    asm volatile("s_waitcnt lgkmcnt(0)" ::: "memory");            \
  } } while (0)
// volatile asm ds_read: compiler cannot attach its own waitcnt to it; all
// ordering vs waits/barriers is explicit.
#define DSR(D, BASE, IMM)                                         \
    asm volatile("ds_read_b128 %0, %1 offset:" #IMM               \
                 : "=v"(D) : "v"(BASE))
// rule #18: asm waitcnt REQUIRES a following sched_barrier(0) or hipcc
// hoists register-only MFMAs above the wait.
#define LGKM(N) do {                                              \
    asm volatile("s_waitcnt lgkmcnt(" #N ")" ::: "memory");       \
    __builtin_amdgcn_sched_barrier(0); } while (0)
#define MFMA16(AR, AV, BV)                                        \
    __builtin_amdgcn_s_setprio(1);                                \
    _Pragma("unroll")                                             \
    for (int mi_ = 0; mi_ < 4; mi_++)                             \
      _Pragma("unroll")                                           \
      for (int ni_ = 0; ni_ < 4; ni_++)                           \
        acc[(AR) + mi_][ni_] = __builtin_amdgcn_mfma_f32_16x16x32_bf16( \
            __builtin_bit_cast(bf16x8, AV[mi_]),                  \
            __builtin_bit_cast(bf16x8, BV[ni_]),                  \
            acc[(AR) + mi_][ni_], 0, 0, 0);                       \
    __builtin_amdgcn_s_setprio(0);

  // prologue: stage all of tile 0, drain, (SM: transform), publish.
  STAGE_A(0, 0, 0); STAGE_B(0, 0, 0); STAGE_A(0, 0, 1); STAGE_B(0, 0, 1);
  asm volatile("s_waitcnt vmcnt(0)" ::: "memory");
  XFORM(0);
  __builtin_amdgcn_s_barrier();
  __builtin_amdgcn_sched_barrier(0);

  for (int kt = 0; kt < NTt; ++kt) {
    const unsigned bufo = (kt & 1) ? 65536u : 0u;   // current buffer (bytes)
    const unsigned bA = bA0 + bufo;
    const unsigned bB = bB0 + bufo;
    const int nb = (kt & 1) ^ 1;         // staging buffer index
    const bool pf = (kt + 1 < NTt);
    f32x4 a0[4], a1[4], b0[4], c0[4], c1[4], d0[4];

    // ---- k-half 0: issue ALL 12 reads, then stage whole next tile ----
    DSR(a0[0], bA, 0);     DSR(a0[1], bA, 1024);
    DSR(a0[2], bA, 2048);  DSR(a0[3], bA, 3072);
    DSR(b0[0], bB, 0);     DSR(b0[1], bB, 1024);
    DSR(b0[2], bB, 2048);  DSR(b0[3], bB, 3072);
    DSR(a1[0], bA, 4096);  DSR(a1[1], bA, 5120);
    DSR(a1[2], bA, 6144);  DSR(a1[3], bA, 7168);
    if (pf) { STAGE_A(nb, kt + 1, 0); STAGE_B(nb, kt + 1, 0);
              STAGE_A(nb, kt + 1, 1); STAGE_B(nb, kt + 1, 1); }

    LGKM(4);              // a0,b0 ready; a1 (4) still in flight
    MFMA16(0, a0, b0)

    // ---- k-half 1 reads fly under the a1xb0 cluster ------------------
    DSR(c0[0], bA, 16384); DSR(c0[1], bA, 17408);
    DSR(c0[2], bA, 18432); DSR(c0[3], bA, 19456);
    DSR(d0[0], bB, 16384); DSR(d0[1], bB, 17408);
    DSR(d0[2], bB, 18432); DSR(d0[3], bB, 19456);
    LGKM(8);              // a1 ready; c0,d0 (8) in flight
    MFMA16(4, a1, b0)

    DSR(c1[0], bA, 20480); DSR(c1[1], bA, 21504);
    DSR(c1[2], bA, 22528); DSR(c1[3], bA, 23552);
    LGKM(4);              // c0,d0 ready; c1 (4) in flight
    MFMA16(0, c0, d0)
    LGKM(0);              // c1 ready
    MFMA16(4, c1, d0)

    // buffer handoff: the ONE barrier per tile. vmcnt(0) retires the 8
    // stages issued at the top of this tile; SM transforms the fresh A.
    if (pf) {
      asm volatile("s_waitcnt vmcnt(0)" ::: "memory");
      XFORM((unsigned)nb << 15);
      __builtin_amdgcn_s_barrier();
      __builtin_amdgcn_sched_barrier(0);
    }
  }

  // epilogue: C/D layout col=lane&15, row=(lane>>4)*4+reg  [m89/m91 verified]
  const size_t cbase = (size_t)z * batchC;
  const int row0 = by * 256 + wm + (lane >> 4) * 4;
  const int col0 = bx * 256 + wn + fr;
#pragma unroll
  for (int mi = 0; mi < 8; mi++) {
#pragma unroll
    for (int i = 0; i < 4; i++) {
      const size_t roff = cbase + (size_t)(row0 + mi * 16 + i) * ldc + col0;
      float rsc = 1.0f;
      if constexpr (SM) rsc = rbuf[wm + (lane >> 4) * 4 + mi * 16 + i];
#pragma unroll
      for (int ni = 0; ni < 4; ni++) {
        float v = acc[mi][ni][i];
        if constexpr (SM) v *= rsc;
        if constexpr (BF16OUT)
          ((u16*)Cout)[roff + ni * 16] = f2bf(v);
        else
          ((float*)Cout)[roff + ni * 16] = v;
      }
    }
  }
#undef STAGE_A
#undef STAGE_B
#undef XFORM
#undef DSR
#undef LGKM
#undef MFMA16
}

// One block per row of 2048 bf16 logits -> stats[row] = {max, 1/sumexp}.
// S is NOT rewritten (PV transforms in LDS) — saves 128MB of traffic.
__global__ __launch_bounds__(256) void row_stats_bf16(
    const u16* __restrict__ SP, float2* __restrict__ st) {
  const size_t row = blockIdx.x;
  const us8* p = (const us8*)(SP + row * 2048);
  const int t = threadIdx.x;
  us8 raw = p[t];
  float v[8];
#pragma unroll
  for (int i = 0; i < 8; i++) v[i] = bf2f(raw[i]);

  float m = v[0];
#pragma unroll
  for (int i = 1; i < 8; i++) m = fmaxf(m, v[i]);
#pragma unroll
  for (int o = 32; o; o >>= 1) m = fmaxf(m, __shfl_xor(m, o, 64));
  __shared__ float redm[4];
  if ((t & 63) == 0) redm[t >> 6] = m;
  __syncthreads();
  m = fmaxf(fmaxf(redm[0], redm[1]), fmaxf(redm[2], redm[3]));

  float sum = 0.f;
#pragma unroll
  for (int i = 0; i < 8; i++) sum += __expf(v[i] - m);
#pragma unroll
  for (int o = 32; o; o >>= 1) sum += __shfl_xor(sum, o, 64);
  __shared__ float reds[4];
  if ((t & 63) == 0) reds[t >> 6] = sum;
  __syncthreads();
  if (t == 0) {
    sum = reds[0] + reds[1] + reds[2] + reds[3];
    st[row] = make_float2(m, 1.0f / sum);
  }
}

extern "C" void kernel_launch(void* const* d_in, const int* in_sizes, int n_in,
                              void* d_out, int out_size, void* d_ws, size_t ws_size,
                              hipStream_t stream) {
  const float* x   = (const float*)d_in[0];  // [8,2048,1024]
  const float* ctx = (const float*)d_in[1];  // [8,2048,1024]
  const float* Wq  = (const float*)d_in[2];  // [1024,1024]
  const float* Wk  = (const float*)d_in[3];
  const float* Wv  = (const float*)d_in[4];
  float* out = (float*)d_out;                // [8,2048,1024] f32

  const size_t NT = 8ull * 2048 * 1024;      // 16,777,216 elements

  // d_ws layout (u16 elements; total 107 MB):
  //   xbf [0,NT)  cbf [NT,2NT)  -> both dead after projections -> S overlays
  //   Vt  [2NT,3NT)   Wqb/Wkb/Wvb [3NT, 3NT+3M)
  //   stats (float2[16384], 128KB) overlays Wqb (dead after projections)
  u16* wsu  = (u16*)d_ws;
  u16* xbf  = wsu;
  u16* Sbuf = wsu;                 // overlays xbf+cbf (67 MB, 8 batches)
  u16* Vt   = wsu + 2 * NT;
  u16* Wqb  = wsu + 3 * NT;        // Wqb,Wkb,Wvb contiguous (1M elems each)
  float2* stats = (float2*)Wqb;    // written AFTER all W uses are done
  // d_out doubles as bf16 Q [0,NT) and K [NT,2NT) until PV overwrites it.
  u16* Qbf = (u16*)d_out;

  dim3 blk(256), gblk(512);

  // 1) all converts, one dispatch (35840 blocks)
  cvt_all<<<dim3(35840), blk, 0, stream>>>(
      (const float4*)x, (const float4*)ctx, (const float4*)Wq,
      (const float4*)Wk, (const float4*)Wv, (us4*)xbf, (us4*)Wqb);

  // 2) [Q|K] projection: M=16384 N=1024 K=1024, z=0/1. nx*ny*nz=4*64*2=512.
  gemm_nt<true, false><<<dim3(512), gblk, 0, stream>>>(
      xbf, Wqb, Qbf, 1024, 1024, 1024, 1024,
      (long)NT, 1024L * 1024, (long)NT, 4, 64, nullptr);
  // Vt[b,e,t] = Wv @ ctx_b^T : M=1024 N=2048 K=1024. nx*ny*nz=8*4*8=256.
  gemm_nt<true, false><<<dim3(256), gblk, 0, stream>>>(
      Wqb + 2 * 1024 * 1024, wsu + NT, Vt, 1024, 1024, 2048, 1024,
      0L, 2048L * 1024, 1024L * 2048, 8, 4, nullptr);

  // 3) S = Q@K^T : 8 batches, M=2048 N=2048 K=1024, bf16 out.
  //    nx*ny*nz = 8*8*8 = 512 blocks; slab=64 = one batch per XCD.
  gemm_nt<true, false><<<dim3(512), gblk, 0, stream>>>(
      Qbf, Qbf + NT, Sbuf, 1024, 1024, 2048, 1024,
      2048L * 1024, 2048L * 1024, 2048L * 2048, 8, 8, nullptr);

  // 4) row stats only (no S rewrite): 16384 rows of 2048
  row_stats_bf16<<<dim3(16384), blk, 0, stream>>>(Sbuf, stats);

  // 5) out = softmax(S)@Vt^T fused: M=2048 N=1024 K=2048, f32 out.
  //    nx*ny*nz=4*8*8=256 -> one batch per XCD. Overwrites dead Q/K.
  gemm_nt<false, true><<<dim3(256), gblk, 0, stream>>>(
      Sbuf, Vt, out, 2048, 2048, 1024, 2048,
      2048L * 2048, 1024L * 2048, 2048L * 1024, 4, 8, stats);
}

// Round 7
// 430.517 us; speedup vs baseline: 1.0126x; 1.0126x over previous
//
#include <hip/hip_runtime.h>

// CrossAttention (B=8, Sq=Skv=2048, D=1024), fp32 in/out, bf16 MFMA compute.
//
// Pipeline (5 dispatches; ws 107 MB; Q AND K parked in d_out as bf16):
//   1) cvt_all: {x,ctx}->bf16 ws; {Wq*(log2e/32),Wk,Wv}->bf16 ws
//   2) [Q|K] = [x|ctx] @ [Wq'|Wk]^T (one batched NT GEMM) -> d_out bf16
//      Vt[b,e,t] = Wv@ctx^T (V transposed so PV is NT)    -> ws
//   3) S' = Q@K^T (8 batches, S' = dots*log2e) -> bf16, overlays xbf+cbf.
//      ST epilogue: per-block-row partial (max, sum 2^(v-max)) on ROUNDED
//      values -> pstats[z][by][row][bx] (1MB, overlays dead Wqb). No
//      separate row_stats dispatch, no extra 64MB read.
//   4) (gone — was row_stats)
//   5) PV GEMM SM=true: prologue combines 8 partials/row into (M, 1/sum)
//      in LDS (hidden under tile-0 staging); staged S' is transformed in
//      LDS to P=2^(s'-M) via v_exp_f32 + v_cvt_pk_bf16_f32 (exp2 domain:
//      no per-element mul; cvt_pk packs 2 elems/instr, RTNE); epilogue
//      multiplies by 1/sum. out f32 -> d_out over dead Q/K.
//
// GEMM core (r5, ~910 TF): 256x256 tile, BK=64, 8 waves (2Mx4N), 128KiB
// static LDS dbuf, counted-lgkm reads-ahead, one barrier per K-tile, asm
// ds_read_b128, XOR swizzle (0 bank conflicts, r2), XCD-aware grid swizzle.
// Grid MUST equal nx*ny*nz exactly and be divisible by 8.

typedef unsigned short u16;
typedef __bf16 bf16x8 __attribute__((ext_vector_type(8)));
typedef float f32x4 __attribute__((ext_vector_type(4)));
typedef u16 us8 __attribute__((ext_vector_type(8)));

__device__ __forceinline__ u16 f2bf(float f) {
  unsigned int u = __float_as_uint(f);
  u += 0x7fffu + ((u >> 16) & 1u);   // round-to-nearest-even
  return (u16)(u >> 16);
}
__device__ __forceinline__ float bf2f(u16 h) {
  return __uint_as_float((unsigned int)h << 16);
}
// v_exp_f32 IS 2^x on gfx9 (ISA §3). Plain asm (not volatile): scheduling
// free, dep-ordered via registers.
__device__ __forceinline__ float exp2a(float x) {
  float r; asm("v_exp_f32 %0, %1" : "=v"(r) : "v"(x)); return r;
}

struct __attribute__((aligned(8))) us4 { u16 x, y, z, w; };

// All fp32->bf16 converts in ONE dispatch (35840 blocks). Wq is scaled by
// log2e/32 so S' = dots*log2e (softmax via 2^x — saves a mul per exp).
__global__ __launch_bounds__(256) void cvt_all(
    const float4* __restrict__ x, const float4* __restrict__ c,
    const float4* __restrict__ wq, const float4* __restrict__ wk,
    const float4* __restrict__ wv,
    us4* __restrict__ dxc, us4* __restrict__ dw) {
  int i = blockIdx.x * 256 + threadIdx.x;
  const float4* s; us4* d; float sc = 1.0f;
  if (i < 4194304)      { s = x + i;            d = dxc + i; }
  else if (i < 8388608) { s = c + (i - 4194304); d = dxc + i; }
  else {
    int j = i - 8388608;
    if (j < 262144)      { s = wq + j;            sc = 0.04508422f; }
    else if (j < 524288) { s = wk + (j - 262144); }
    else                 { s = wv + (j - 524288); }
    d = dw + j;
  }
  float4 v = *s;
  us4 o{f2bf(v.x * sc), f2bf(v.y * sc), f2bf(v.z * sc), f2bf(v.w * sc)};
  *d = o;
}

// C-style casts: static_cast cannot both drop const and change address space.
__device__ __forceinline__ void gload16(const u16* g, u16* l) {
  __builtin_amdgcn_global_load_lds(
      (const __attribute__((address_space(1))) unsigned int*)g,
      (__attribute__((address_space(3))) unsigned int*)l,
      16, 0, 0);
}

// NT GEMM: C[m,n] = sum_k A[m,k]*B[n,k].  A:[M][lda] B:[N][ldb] bf16
// row-major. 1D grid of EXACTLY nx*ny*nz blocks (divisible by 8), 512 thr.
// ST: epilogue emits per-block-row softmax partials to pst[z][by][row][bx].
// SM: prologue combines partials; staged A transformed to P in LDS;
//     epilogue scales by 1/sum.
template <bool BF16OUT, bool SM, bool ST>
__global__ __launch_bounds__(512, 2) void gemm_nt(
    const u16* __restrict__ A, const u16* __restrict__ B, void* __restrict__ Cout,
    int lda, int ldb, int ldc, int K,
    long batchA, long batchB, long batchC, int nx, int ny,
    float2* __restrict__ pst) {
  __shared__ u16 lds[65536];   // 128 KiB static
  __shared__ float smax_l[256];  // SM: per-row max
  __shared__ float rbuf[256];    // SM: per-row 1/sum
  // layout (u16 offs): buf b at b*32768; A k-half h at +h*8192 (256x32),
  // B at +16384 (+h*8192). Within a k-half: row r at r*32, 4 slots of 8.

  const int p    = blockIdx.x;
  const int slab = gridDim.x >> 3;
  const int gid  = (p & 7) * slab + (p >> 3);
  const int bx   = gid % nx;
  const int t2   = gid / nx;
  const int by   = t2 % ny;
  const int z    = t2 / ny;

  const int tid  = threadIdx.x;          // 0..511
  const int lane = tid & 63;
  const int wv   = tid >> 6;             // wave 0..7

  const u16* Ab = A + (size_t)z * batchA + (size_t)by * 256 * lda;
  const u16* Bb = B + (size_t)z * batchB + (size_t)bx * 256 * ldb;

  // staging: 512 threads, 4/row (64-B runs), 2 instrs cover 256 rows.
  // global col-group pre-swizzled: c = (tid&3) ^ ((row>>1)&3), row=tid>>2.
  const int srow = tid >> 2;                              // 0..127
  const int scol = ((tid & 3) ^ ((tid >> 3) & 3)) * 8;    // swizzled source

  const u16* gA = Ab + (size_t)srow * lda + scol;
  const u16* gB = Bb + (size_t)srow * ldb + scol;
  const size_t a128 = (size_t)128 * lda, b128 = (size_t)128 * ldb;

  u16* dA = &lds[tid * 8];           // + buf*32768 + h*8192 (+4096 instr 1)
  u16* dB = &lds[16384 + tid * 8];

  // fragment addressing (per wave: 128x64 tile, 8x4 frags of 16x16x32)
  const int fr = lane & 15;              // m (A) / n (B) within 16
  const int xw = (((lane >> 4) ^ ((lane >> 1) & 3)) * 8);
  const int wm = (wv >> 2) * 128;        // wave m-offset (0 or 128)
  const int wn = (wv & 3) * 64;          // wave n-offset (0..192)
  const int rA = (wm + fr) * 32 + xw;    // u16 offset within A k-half
  const int rB = (wn + fr) * 32 + xw;

  // byte addresses for inline-asm ds_read (buffer 0; buffer 1 = +65536 B)
  const unsigned ldsb = (unsigned)(size_t)&lds[0];
  const unsigned bA0 = ldsb + (unsigned)(rA * 2);
  const unsigned bB0 = ldsb + 32768u + (unsigned)(rB * 2);

  f32x4 acc[8][4];
#pragma unroll
  for (int i = 0; i < 8; i++)
#pragma unroll
    for (int j = 0; j < 4; j++) acc[i][j] = (f32x4)0.f;

  const int NTt = K >> 6;                // BK=64 tiles
  float mrow0 = 0.f, mrow1 = 0.f;        // SM: maxes of this thread's A rows

#define STAGE_A(BUF, KT, H) do {                                  \
    const u16* g_ = gA + (size_t)(KT) * 64 + (H) * 32;            \
    u16* d_ = dA + ((BUF) << 15) + (H) * 8192;                    \
    gload16(g_, d_); gload16(g_ + a128, d_ + 4096); } while (0)
#define STAGE_B(BUF, KT, H) do {                                  \
    const u16* g_ = gB + (size_t)(KT) * 64 + (H) * 32;            \
    u16* d_ = dB + ((BUF) << 15) + (H) * 8192;                    \
    gload16(g_, d_); gload16(g_ + b128, d_ + 4096); } while (0)
// SM: transform this thread's 4 staged A-slots in buffer BUFO (u16 off):
// P = 2^(s' - mrow). Slots: {+0:(h0,srow)} {+4096:(h0,srow+128)}
// {+8192:(h1,srow)} {+12288:(h1,srow+128)}. Own-slot only (per-wave
// vmcnt(0) ordered own gloads). bf16 halves extracted with 1-op shifts;
// packed back 2-at-a-time with v_cvt_pk_bf16_f32 (RTNE).
#define XFORM(BUFO) do { if constexpr (SM) {                      \
    u16* xb_ = dA + (BUFO);                                       \
    _Pragma("unroll")                                             \
    for (int s_ = 0; s_ < 4; s_++) {                              \
      uint4* p_ = (uint4*)(xb_ + (s_ & 1) * 4096 + (s_ >> 1) * 8192); \
      const float mm_ = (s_ & 1) ? mrow1 : mrow0;                 \
      uint4 v_ = *p_;                                             \
      unsigned w_[4] = {v_.x, v_.y, v_.z, v_.w};                  \
      _Pragma("unroll")                                           \
      for (int k_ = 0; k_ < 4; k_++) {                            \
        float lo_ = exp2a(__uint_as_float(w_[k_] << 16) - mm_);   \
        float hi_ = exp2a(__uint_as_float(w_[k_] & 0xffff0000u) - mm_); \
        asm("v_cvt_pk_bf16_f32 %0, %1, %2"                        \
            : "=v"(w_[k_]) : "v"(lo_), "v"(hi_));                 \
      }                                                           \
      *p_ = make_uint4(w_[0], w_[1], w_[2], w_[3]);               \
    }                                                             \
    asm volatile("s_waitcnt lgkmcnt(0)" ::: "memory");            \
  } } while (0)
#define DSR(D, BASE, IMM)                                         \
    asm volatile("ds_read_b128 %0, %1 offset:" #IMM               \
                 : "=v"(D) : "v"(BASE))
#define LGKM(N) do {                                              \
    asm volatile("s_waitcnt lgkmcnt(" #N ")" ::: "memory");       \
    __builtin_amdgcn_sched_barrier(0); } while (0)
#define MFMA16(AR, AV, BV)                                        \
    __builtin_amdgcn_s_setprio(1);                                \
    _Pragma("unroll")                                             \
    for (int mi_ = 0; mi_ < 4; mi_++)                             \
      _Pragma("unroll")                                           \
      for (int ni_ = 0; ni_ < 4; ni_++)                           \
        acc[(AR) + mi_][ni_] = __builtin_amdgcn_mfma_f32_16x16x32_bf16( \
            __builtin_bit_cast(bf16x8, AV[mi_]),                  \
            __builtin_bit_cast(bf16x8, BV[ni_]),                  \
            acc[(AR) + mi_][ni_], 0, 0, 0);                       \
    __builtin_amdgcn_s_setprio(0);

  // prologue: stage all of tile 0; (SM: combine row partials while loads
  // fly); drain; (SM: transform); publish.
  STAGE_A(0, 0, 0); STAGE_B(0, 0, 0); STAGE_A(0, 0, 1); STAGE_B(0, 0, 1);
  if constexpr (SM) {
    if (tid < 256) {
      const float2* pg = pst + (((size_t)z * 8 + by) * 256 + tid) * 8;
      float2 q[8];
#pragma unroll
      for (int j = 0; j < 8; j++) q[j] = pg[j];
      float M = q[0].x;
#pragma unroll
      for (int j = 1; j < 8; j++) M = fmaxf(M, q[j].x);
      float Ssum = 0.f;
#pragma unroll
      for (int j = 0; j < 8; j++) Ssum += q[j].y * exp2a(q[j].x - M);
      smax_l[tid] = M;
      rbuf[tid] = 1.0f / Ssum;
    }
    __syncthreads();
    mrow0 = smax_l[srow];
    mrow1 = smax_l[srow + 128];
  }
  asm volatile("s_waitcnt vmcnt(0)" ::: "memory");
  XFORM(0);
  __builtin_amdgcn_s_barrier();
  __builtin_amdgcn_sched_barrier(0);

  for (int kt = 0; kt < NTt; ++kt) {
    const unsigned bufo = (kt & 1) ? 65536u : 0u;   // current buffer (bytes)
    const unsigned bA = bA0 + bufo;
    const unsigned bB = bB0 + bufo;
    const int nb = (kt & 1) ^ 1;         // staging buffer index
    const bool pf = (kt + 1 < NTt);
    f32x4 a0[4], a1[4], b0[4], c0[4], c1[4], d0[4];

    // ---- k-half 0: issue ALL 12 reads, then stage whole next tile ----
    DSR(a0[0], bA, 0);     DSR(a0[1], bA, 1024);
    DSR(a0[2], bA, 2048);  DSR(a0[3], bA, 3072);
    DSR(b0[0], bB, 0);     DSR(b0[1], bB, 1024);
    DSR(b0[2], bB, 2048);  DSR(b0[3], bB, 3072);
    DSR(a1[0], bA, 4096);  DSR(a1[1], bA, 5120);
    DSR(a1[2], bA, 6144);  DSR(a1[3], bA, 7168);
    if (pf) { STAGE_A(nb, kt + 1, 0); STAGE_B(nb, kt + 1, 0);
              STAGE_A(nb, kt + 1, 1); STAGE_B(nb, kt + 1, 1); }

    LGKM(4);              // a0,b0 ready; a1 (4) still in flight
    MFMA16(0, a0, b0)

    // ---- k-half 1 reads fly under the a1xb0 cluster ------------------
    DSR(c0[0], bA, 16384); DSR(c0[1], bA, 17408);
    DSR(c0[2], bA, 18432); DSR(c0[3], bA, 19456);
    DSR(d0[0], bB, 16384); DSR(d0[1], bB, 17408);
    DSR(d0[2], bB, 18432); DSR(d0[3], bB, 19456);
    LGKM(8);              // a1 ready; c0,d0 (8) in flight
    MFMA16(4, a1, b0)

    DSR(c1[0], bA, 20480); DSR(c1[1], bA, 21504);
    DSR(c1[2], bA, 22528); DSR(c1[3], bA, 23552);
    LGKM(4);              // c0,d0 ready; c1 (4) in flight
    MFMA16(0, c0, d0)
    LGKM(0);              // c1 ready
    MFMA16(4, c1, d0)

    // buffer handoff: the ONE barrier per tile. vmcnt(0) retires the 8
    // stages issued at the top of this tile; SM transforms the fresh A.
    if (pf) {
      asm volatile("s_waitcnt vmcnt(0)" ::: "memory");
      XFORM((unsigned)nb << 15);
      __builtin_amdgcn_s_barrier();
      __builtin_amdgcn_sched_barrier(0);
    }
  }

  // epilogue: C/D layout col=lane&15, row=(lane>>4)*4+reg  [m89/m91 verified]
  const size_t cbase = (size_t)z * batchC;
  const int row0 = by * 256 + wm + (lane >> 4) * 4;
  const int col0 = bx * 256 + wn + fr;
  float2* pstl = (float2*)lds;           // ST: [256][4] wave-col partials
  if constexpr (ST) __syncthreads();     // protect LDS reuse
#pragma unroll
  for (int mi = 0; mi < 8; mi++) {
#pragma unroll
    for (int i = 0; i < 4; i++) {
      const size_t roff = cbase + (size_t)(row0 + mi * 16 + i) * ldc + col0;
      float rsc = 1.0f;
      if constexpr (SM) rsc = rbuf[wm + (lane >> 4) * 4 + mi * 16 + i];
      float vr[4];
#pragma unroll
      for (int ni = 0; ni < 4; ni++) {
        float v = acc[mi][ni][i];
        if constexpr (SM) v *= rsc;
        if constexpr (BF16OUT) {
          u16 h = f2bf(v);
          ((u16*)Cout)[roff + ni * 16] = h;
          vr[ni] = bf2f(h);              // stats on ROUNDED values
        } else {
          ((float*)Cout)[roff + ni * 16] = v;
        }
      }
      if constexpr (ST) {
        // row = 16 fr-lanes x 4 ni = this wave's 64 cols; reduce over fr.
        float mx = fmaxf(fmaxf(vr[0], vr[1]), fmaxf(vr[2], vr[3]));
#pragma unroll
        for (int o = 1; o <= 8; o <<= 1) mx = fmaxf(mx, __shfl_xor(mx, o, 64));
        float ls = 0.f;
#pragma unroll
        for (int ni = 0; ni < 4; ni++) ls += exp2a(vr[ni] - mx);
#pragma unroll
        for (int o = 1; o <= 8; o <<= 1) ls += __shfl_xor(ls, o, 64);
        if (fr == 0)
          pstl[(wm + (lane >> 4) * 4 + mi * 16 + i) * 4 + (wv & 3)] =
              make_float2(mx, ls);
      }
    }
  }
  if constexpr (ST) {
    __syncthreads();
    if (tid < 256) {   // combine 4 wave-col partials -> global per-bx partial
      float2 q0 = pstl[tid * 4], q1 = pstl[tid * 4 + 1];
      float2 q2 = pstl[tid * 4 + 2], q3 = pstl[tid * 4 + 3];
      float M = fmaxf(fmaxf(q0.x, q1.x), fmaxf(q2.x, q3.x));
      float Ssum = q0.y * exp2a(q0.x - M) + q1.y * exp2a(q1.x - M) +
                   q2.y * exp2a(q2.x - M) + q3.y * exp2a(q3.x - M);
      pst[(((size_t)z * 8 + by) * 256 + tid) * 8 + bx] = make_float2(M, Ssum);
    }
  }
#undef STAGE_A
#undef STAGE_B
#undef XFORM
#undef DSR
#undef LGKM
#undef MFMA16
}

extern "C" void kernel_launch(void* const* d_in, const int* in_sizes, int n_in,
                              void* d_out, int out_size, void* d_ws, size_t ws_size,
                              hipStream_t stream) {
  const float* x   = (const float*)d_in[0];  // [8,2048,1024]
  const float* ctx = (const float*)d_in[1];  // [8,2048,1024]
  const float* Wq  = (const float*)d_in[2];  // [1024,1024]
  const float* Wk  = (const float*)d_in[3];
  const float* Wv  = (const float*)d_in[4];
  float* out = (float*)d_out;                // [8,2048,1024] f32

  const size_t NT = 8ull * 2048 * 1024;      // 16,777,216 elements

  // d_ws layout (u16 elements; total 107 MB):
  //   xbf [0,NT)  cbf [NT,2NT)  -> both dead after projections -> S overlays
  //   Vt  [2NT,3NT)   Wqb/Wkb/Wvb [3NT, 3NT+3M)
  //   pstats (float2[8][8][256][8], 1MB) overlays Wqb (dead after proj)
  u16* wsu  = (u16*)d_ws;
  u16* xbf  = wsu;
  u16* Sbuf = wsu;                 // overlays xbf+cbf (67 MB, 8 batches)
  u16* Vt   = wsu + 2 * NT;
  u16* Wqb  = wsu + 3 * NT;        // Wqb,Wkb,Wvb contiguous (1M elems each)
  float2* pstats = (float2*)Wqb;   // written by S-GEMM (after all W uses)
  // d_out doubles as bf16 Q [0,NT) and K [NT,2NT) until PV overwrites it.
  u16* Qbf = (u16*)d_out;

  dim3 blk(256), gblk(512);

  // 1) all converts, one dispatch (35840 blocks)
  cvt_all<<<dim3(35840), blk, 0, stream>>>(
      (const float4*)x, (const float4*)ctx, (const float4*)Wq,
      (const float4*)Wk, (const float4*)Wv, (us4*)xbf, (us4*)Wqb);

  // 2) [Q|K] projection: M=16384 N=1024 K=1024, z=0/1. nx*ny*nz=4*64*2=512.
  gemm_nt<true, false, false><<<dim3(512), gblk, 0, stream>>>(
      xbf, Wqb, Qbf, 1024, 1024, 1024, 1024,
      (long)NT, 1024L * 1024, (long)NT, 4, 64, nullptr);
  // Vt[b,e,t] = Wv @ ctx_b^T : M=1024 N=2048 K=1024. nx*ny*nz=8*4*8=256.
  gemm_nt<true, false, false><<<dim3(256), gblk, 0, stream>>>(
      Wqb + 2 * 1024 * 1024, wsu + NT, Vt, 1024, 1024, 2048, 1024,
      0L, 2048L * 1024, 1024L * 2048, 8, 4, nullptr);

  // 3) S' = Q@K^T (exp2 domain): 8 batches, M=2048 N=2048 K=1024, bf16 out
  //    + per-bx row partials. nx*ny*nz = 8*8*8 = 512; slab=64 = 1 batch/XCD.
  gemm_nt<true, false, true><<<dim3(512), gblk, 0, stream>>>(
      Qbf, Qbf + NT, Sbuf, 1024, 1024, 2048, 1024,
      2048L * 1024, 2048L * 1024, 2048L * 2048, 8, 8, pstats);

  // 5) out = softmax(S)@Vt^T fused: M=2048 N=1024 K=2048, f32 out.
  //    nx*ny*nz=4*8*8=256 -> one batch per XCD. Overwrites dead Q/K.
  gemm_nt<false, true, false><<<dim3(256), gblk, 0, stream>>>(
      Sbuf, Vt, out, 2048, 2048, 1024, 2048,
      2048L * 2048, 1024L * 2048, 2048L * 1024, 4, 8, pstats);
}